// Round 7
// baseline (174.459 us; speedup 1.0000x reference)
//
#include <hip/hip_runtime.h>
#include <math.h>

#define NB 1024
#define C_CAP 2048
#define BLK1 512
#define BLK2 1024
#define LCAP2 2048           // per half-row pre-list cap (expected ~1450)
#define FLOORB 682           // bin_of(1.9922); N(0,1): E[suffix] ~ 2900 >= Kp_max=1023
#define BIN_SCALE ((float)NB / 12.0f)
#define BOUND 1.9921875f     // -6 + FLOORB*12/NB

__device__ __forceinline__ int bin_of(float x) {
  int b = (int)floorf((x + 6.0f) * BIN_SCALE);
  return min(max(b, 0), NB - 1);
}
__device__ __forceinline__ unsigned long long pack_vi(float v, int idx) {
  return ((unsigned long long)__float_as_uint(v) << 32) | (unsigned int)idx;
}
// order key: value desc, idx asc
__device__ __forceinline__ unsigned long long okey(float v, int idx) {
  unsigned int u = __float_as_uint(v);
  u = (u & 0x80000000u) ? ~u : (u | 0x80000000u);
  return ((unsigned long long)u << 32) | (unsigned long long)(0x7fffffffu - (unsigned int)idx);
}
__device__ __forceinline__ float okey_val(unsigned long long k) {
  unsigned int hi = (unsigned int)(k >> 32);
  unsigned int u = (hi & 0x80000000u) ? (hi & 0x7fffffffu) : ~hi;
  return __uint_as_float(u);
}
__device__ __forceinline__ int okey_idx(unsigned long long k) {
  return (int)(0x7fffffffu - (unsigned int)k);
}

// ---- k1: stream half-row; fixed-shift sumexp + ballot-aggregated pre-collect ----
__global__ __launch_bounds__(BLK1)
void k1_scan(const float* __restrict__ logits, int V, int halfElems,
             unsigned long long* __restrict__ plist, int* __restrict__ pcnt,
             float* __restrict__ psum) {
  const int row = blockIdx.y, half = blockIdx.x, tid = threadIdx.x;
  const int lane = tid & 63;
  const float* lrow = logits + (size_t)row * V;
  const int start = half * halfElems;
  const int end = min(start + halfElems, V);
  __shared__ unsigned long long lst[LCAP2];
  __shared__ float rs[BLK1];
  __shared__ int lcnt;
  if (tid == 0) lcnt = 0;
  __syncthreads();
  float sum = 0.0f;
  const int n = max(end - start, 0);
  const int n4 = n >> 2;
  const float4* p4 = (const float4*)(lrow + start);
  int i = tid;
  for (; i + BLK1 < n4; i += 2 * BLK1) {
    float4 a = p4[i], b2 = p4[i + BLK1];
    float va[8] = {a.x, a.y, a.z, a.w, b2.x, b2.y, b2.z, b2.w};
    int ia[8];
    #pragma unroll
    for (int c2 = 0; c2 < 4; c2++) { ia[c2] = (i << 2) + c2; ia[c2 + 4] = ((i + BLK1) << 2) + c2; }
    #pragma unroll
    for (int c2 = 0; c2 < 8; c2++) {
      float x = va[c2];
      sum += __expf(fminf(x, 70.0f) - 6.0f);
      bool pred = (x >= BOUND);
      unsigned long long mk = __ballot(pred);
      if (mk) {
        int leader = __ffsll((long long)mk) - 1;
        int base = 0;
        if (lane == leader) base = atomicAdd(&lcnt, __popcll(mk));
        base = __shfl(base, leader, 64);
        if (pred) {
          int p = base + __popcll(mk & ((1ull << lane) - 1ull));
          if (p < LCAP2) lst[p] = pack_vi(x, start + ia[c2]);
        }
      }
    }
  }
  for (; i < n4; i += BLK1) {
    float4 a = p4[i];
    float va[4] = {a.x, a.y, a.z, a.w};
    #pragma unroll
    for (int c2 = 0; c2 < 4; c2++) {
      float x = va[c2];
      sum += __expf(fminf(x, 70.0f) - 6.0f);
      bool pred = (x >= BOUND);
      unsigned long long mk = __ballot(pred);
      if (mk) {
        int leader = __ffsll((long long)mk) - 1;
        int base = 0;
        if (lane == leader) base = atomicAdd(&lcnt, __popcll(mk));
        base = __shfl(base, leader, 64);
        if (pred) {
          int p = base + __popcll(mk & ((1ull << lane) - 1ull));
          if (p < LCAP2) lst[p] = pack_vi(x, start + (i << 2) + c2);
        }
      }
    }
  }
  for (int j = (n4 << 2) + tid; j < n; j += BLK1) {
    float x = lrow[start + j];
    sum += __expf(fminf(x, 70.0f) - 6.0f);
    bool pred = (x >= BOUND);
    unsigned long long mk = __ballot(pred);
    if (mk) {
      int leader = __ffsll((long long)mk) - 1;
      int base = 0;
      if (lane == leader) base = atomicAdd(&lcnt, __popcll(mk));
      base = __shfl(base, leader, 64);
      if (pred) {
        int p = base + __popcll(mk & ((1ull << lane) - 1ull));
        if (p < LCAP2) lst[p] = pack_vi(x, start + j);
      }
    }
  }
  __syncthreads();
  rs[tid] = sum;
  __syncthreads();
  for (int s = BLK1 / 2; s > 0; s >>= 1) {
    if (tid < s) rs[tid] += rs[tid + s];
    __syncthreads();
  }
  const size_t rc = (size_t)row * 2 + half;
  if (tid == 0) { psum[rc] = rs[0]; pcnt[rc] = lcnt; }
  int m = min(lcnt, LCAP2);
  unsigned long long* prow = plist + rc * LCAP2;
  for (int j = tid; j < m; j += BLK1) prow[j] = lst[j];
}

// ---- k2: hist from pre-lists -> bstar -> counting sort -> chain -> sample ----
__global__ __launch_bounds__(BLK2)
void k2_fused(const float* __restrict__ logits,
              const float* __restrict__ temperature,
              const float* __restrict__ min_p,
              const int* __restrict__ top_k,
              const float* __restrict__ top_p,
              const float* __restrict__ q,
              const int* __restrict__ nl_ptr,
              int V, int B,
              const unsigned long long* __restrict__ plist,
              const int* __restrict__ pcnt,
              const float* __restrict__ psum,
              float* __restrict__ out) {
  const int row = blockIdx.x, tid = threadIdx.x;
  __shared__ int h[NB + 1];
  __shared__ int cur[NB];
  __shared__ unsigned long long lst[2 * LCAP2];
  __shared__ unsigned long long bkt[C_CAP];
  __shared__ float sv[C_CAP];
  __shared__ int   si[C_CAP];
  __shared__ float ss[C_CAP];
  __shared__ float st[BLK2];
  __shared__ float rf[BLK2], rf2[BLK2];
  __shared__ int   ri[BLK2];
  __shared__ int   s_fail, s_b;
  __shared__ float s_lse;

  for (int i = tid; i < NB; i += BLK2) { h[i] = 0; cur[i] = 0; }
  if (tid == 0) { s_b = 0; h[NB] = 0; }
  __syncthreads();

  const int p0 = pcnt[(size_t)row * 2], p1 = pcnt[(size_t)row * 2 + 1];
  const int c0 = min(p0, LCAP2), c1 = min(p1, LCAP2);
  const int tot = c0 + c1;
  int nl = nl_ptr[0];
  int ke = top_k[row]; ke = min(max(ke, 1), V);
  const int Kp = max(ke, nl);
  const bool fast = (p0 <= LCAP2) && (p1 <= LCAP2) && (tot >= Kp);

  if (tid == 0) s_lse = 6.0f + logf(psum[(size_t)row * 2] + psum[(size_t)row * 2 + 1]);

  const float* lrow = logits + (size_t)row * V;
  const int n4 = V >> 2;
  const float4* p4 = (const float4*)lrow;

  if (fast) {
    // load pre-lists to LDS, histogram candidate bins
    const unsigned long long* pr0 = plist + (size_t)row * 2 * LCAP2;
    const unsigned long long* pr1 = pr0 + LCAP2;
    for (int j = tid; j < c0; j += BLK2) lst[j] = pr0[j];
    for (int j = tid; j < c1; j += BLK2) lst[c0 + j] = pr1[j];
    __syncthreads();
    for (int j = tid; j < tot; j += BLK2) {
      float x = __uint_as_float((unsigned int)(lst[j] >> 32));
      atomicAdd(&h[bin_of(x)], 1);
    }
  } else {
    // full histogram from the row (rare fallback)
    for (int ii = tid; ii < n4; ii += BLK2) {
      float4 a4 = p4[ii];
      atomicAdd(&h[bin_of(a4.x)], 1); atomicAdd(&h[bin_of(a4.y)], 1);
      atomicAdd(&h[bin_of(a4.z)], 1); atomicAdd(&h[bin_of(a4.w)], 1);
    }
    for (int j = (n4 << 2) + tid; j < V; j += BLK2)
      atomicAdd(&h[bin_of(lrow[j])], 1);
  }
  __syncthreads();

  // suffix-inclusive scan: h[i] = count in bins >= i
  for (int off = 1; off < NB; off <<= 1) {
    int t0 = (tid + off < NB) ? h[tid + off] : 0;
    __syncthreads();
    h[tid] += t0;
    __syncthreads();
  }
  if (h[tid] >= Kp) atomicMax(&s_b, tid);
  __syncthreads();
  const int bstar = s_b;
  int c = min(h[bstar], C_CAP); if (c < 1) c = 1;

  // ingest into bin-grouped positions (base = h[b+1], per-bin cursor)
  if (fast) {
    for (int j = tid; j < tot; j += BLK2) {
      unsigned long long kk = lst[j];
      float x = __uint_as_float((unsigned int)(kk >> 32));
      int idx = (int)(unsigned int)kk;
      int b = bin_of(x);
      if (b >= bstar) {
        int a = atomicAdd(&cur[b], 1);
        int pos = h[b + 1] + a;
        if (pos < C_CAP) bkt[pos] = okey(x, idx);
      }
    }
  } else {
    for (int ii = tid; ii < n4; ii += BLK2) {
      float4 a4 = p4[ii];
      float va[4] = {a4.x, a4.y, a4.z, a4.w};
      #pragma unroll
      for (int c2 = 0; c2 < 4; c2++) {
        int b = bin_of(va[c2]);
        if (b >= bstar) {
          int a = atomicAdd(&cur[b], 1);
          int pos = h[b + 1] + a;
          if (pos < C_CAP) bkt[pos] = okey(va[c2], (ii << 2) + c2);
        }
      }
    }
    for (int j = (n4 << 2) + tid; j < V; j += BLK2) {
      float x = lrow[j];
      int b = bin_of(x);
      if (b >= bstar) {
        int a = atomicAdd(&cur[b], 1);
        int pos = h[b + 1] + a;
        if (pos < C_CAP) bkt[pos] = okey(x, j);
      }
    }
  }
  __syncthreads();

  // exact rank within bin -> sorted sv/si
  for (int pos = tid; pos < c; pos += BLK2) {
    unsigned long long k0 = bkt[pos];
    float v = okey_val(k0);
    int b = bin_of(v);
    int gs = h[b + 1];
    int ge = min(h[b], c);
    int rk = 0;
    for (int j = gs; j < ge; j++) if (bkt[j] > k0) rk++;
    int fin = gs + rk;
    sv[fin] = v; si[fin] = okey_idx(k0);
  }
  __syncthreads();

  // ---- filter chain ----
  float temp = temperature[row];
  bool ug = (temp < 1e-5f);
  float rt = 1.0f / (ug ? 1.0f : temp);
  float mp = min_p[row], tp = top_p[row];
  ke = min(ke, c);
  float v0 = sv[0];
  float lt0 = v0 * rt;

  float ltk = sv[ke - 1] * rt;
  float kth = (expf(ltk - lt0) >= mp) ? ltk : -INFINITY;

  if (tid == 0) s_fail = c;
  __syncthreads();
  for (int ii = tid; ii < c; ii += BLK2) {
    float ltj = sv[ii] * rt;
    if (!((expf(ltj - lt0) >= mp) && (ltj >= kth))) { atomicMin(&s_fail, ii); break; }
  }
  __syncthreads();
  int n1 = s_fail; if (n1 < 1) n1 = 1;
  __syncthreads();

  // segmented inclusive prefix scan of p_j over [0, c)
  int L = (c + BLK2 - 1) / BLK2;
  int base = tid * L;
  int lim = min(base + L, c);
  float run = 0.0f;
  for (int j = base; j < lim; j++) {
    float pj = (j < n1) ? expf(sv[j] * rt - lt0) : 0.0f;
    run += pj; ss[j] = run;
  }
  st[tid] = run;
  __syncthreads();
  for (int off = 1; off < BLK2; off <<= 1) {
    float t0 = (tid >= off) ? st[tid - off] : 0.0f;
    __syncthreads();
    st[tid] += t0;
    __syncthreads();
  }
  float offv = (tid > 0) ? st[tid - 1] : 0.0f;
  for (int j = base; j < lim; j++) ss[j] += offv;
  __syncthreads();
  float Z1 = ss[n1 - 1];

  if (tid == 0) s_fail = n1;
  __syncthreads();
  for (int ii = tid; ii < n1; ii += BLK2) {
    if (ii > 0 && !((1.0f - ss[ii - 1] / Z1) > (1.0f - tp))) { atomicMin(&s_fail, ii); break; }
  }
  __syncthreads();
  int n2 = s_fail; if (n2 < 1) n2 = 1;
  __syncthreads();
  float Z2 = ss[n2 - 1];

  const float* qrow = q + (size_t)row * V;
  float bsc = -INFINITY; int bidx = 0x7fffffff; float bval = 0.0f;
  for (int ii = tid; ii < n2; ii += BLK2) {
    float pj = expf(sv[ii] * rt - lt0);
    float qv = qrow[si[ii]];
    qv = fminf(fmaxf(qv, 1e-10f), 1.0f);
    float sc = (pj / Z2) / (-logf(qv));
    if (sc > bsc || (sc == bsc && si[ii] < bidx)) { bsc = sc; bidx = si[ii]; bval = sv[ii]; }
  }
  rf[tid] = bsc; ri[tid] = bidx; rf2[tid] = bval;
  __syncthreads();
  for (int s = BLK2 / 2; s > 0; s >>= 1) {
    if (tid < s) {
      if (rf[tid + s] > rf[tid] ||
          (rf[tid + s] == rf[tid] && ri[tid + s] < ri[tid])) {
        rf[tid] = rf[tid + s]; ri[tid] = ri[tid + s]; rf2[tid] = rf2[tid + s];
      }
    }
    __syncthreads();
  }
  int sampled = ug ? si[0] : ri[0];
  float val_s = ug ? sv[0] : rf2[0];
  float lse = s_lse;
  float tok_lp = val_s - lse;
  __syncthreads();

  if (tid == 0) s_fail = c;
  __syncthreads();
  for (int ii = tid; ii < c; ii += BLK2)
    if (!((sv[ii] - lse) >= tok_lp)) { atomicMin(&s_fail, ii); break; }
  __syncthreads();
  int rank = s_fail;

  int W = nl + 1;
  if (tid == 0) {
    out[row] = (float)sampled;
    out[B + row * W] = (float)sampled;
    out[B + B * W + row * W] = tok_lp;
    out[B + 2 * B * W + row] = (float)rank;
  }
  for (int t = tid; t < nl; t += BLK2) {
    out[B + row * W + 1 + t] = (float)si[t];
    out[B + B * W + row * W + 1 + t] = sv[t] - lse;
  }
}

extern "C" void kernel_launch(void* const* d_in, const int* in_sizes, int n_in,
                              void* d_out, int out_size, void* d_ws, size_t ws_size,
                              hipStream_t stream) {
  const float* logits      = (const float*)d_in[0];
  const float* temperature = (const float*)d_in[1];
  const float* min_p       = (const float*)d_in[2];
  const int*   top_k       = (const int*)d_in[3];
  const float* top_p       = (const float*)d_in[4];
  const float* q           = (const float*)d_in[5];
  const int*   nl_ptr      = (const int*)d_in[6];

  int B = in_sizes[1];
  int V = in_sizes[0] / B;
  float* out = (float*)d_out;
  int halfElems = (((V + 1) / 2) + 3) & ~3;

  unsigned char* w = (unsigned char*)d_ws;
  unsigned long long* plist = (unsigned long long*)w; w += (size_t)B * 2 * LCAP2 * sizeof(unsigned long long);
  int* pcnt = (int*)w;                                w += (size_t)B * 2 * sizeof(int);
  float* psum = (float*)w;                            w += (size_t)B * 2 * sizeof(float);

  hipLaunchKernelGGL(k1_scan, dim3(2, B), dim3(BLK1), 0, stream,
                     logits, V, halfElems, plist, pcnt, psum);
  hipLaunchKernelGGL(k2_fused, dim3(B), dim3(BLK2), 0, stream,
                     logits, temperature, min_p, top_k, top_p, q, nl_ptr,
                     V, B, plist, pcnt, psum, out);
}

// Round 8
// 166.612 us; speedup vs baseline: 1.0471x; 1.0471x over previous
//
#include <hip/hip_runtime.h>
#include <math.h>

#define NB 1024
#define C_CAP 2048
#define BLK1 512
#define BLK2 512
#define NWAVES1 (BLK1 / 64)
#define WSEG 512             // per-wave segment cap (E[matches/wave]~181, +25 sigma)
#define LCAP2 2048           // per half-row pre-list cap (expected ~1450)
#define FLOORB 682           // bin_of(1.9922); N(0,1): E[suffix] ~ 2900 >= Kp_max=1023
#define BIN_SCALE ((float)NB / 12.0f)
#define BOUND 1.9921875f     // -6 + FLOORB*12/NB

__device__ __forceinline__ int bin_of(float x) {
  int b = (int)floorf((x + 6.0f) * BIN_SCALE);
  return min(max(b, 0), NB - 1);
}
__device__ __forceinline__ unsigned long long pack_vi(float v, int idx) {
  return ((unsigned long long)__float_as_uint(v) << 32) | (unsigned int)idx;
}
// order key: value desc, idx asc
__device__ __forceinline__ unsigned long long okey(float v, int idx) {
  unsigned int u = __float_as_uint(v);
  u = (u & 0x80000000u) ? ~u : (u | 0x80000000u);
  return ((unsigned long long)u << 32) | (unsigned long long)(0x7fffffffu - (unsigned int)idx);
}
__device__ __forceinline__ float okey_val(unsigned long long k) {
  unsigned int hi = (unsigned int)(k >> 32);
  unsigned int u = (hi & 0x80000000u) ? (hi & 0x7fffffffu) : ~hi;
  return __uint_as_float(u);
}
__device__ __forceinline__ int okey_idx(unsigned long long k) {
  return (int)(0x7fffffffu - (unsigned int)k);
}

// ---- k1: stream half-row; sumexp + per-wave-segment pre-collect ----
__global__ __launch_bounds__(BLK1)
void k1_scan(const float* __restrict__ logits, int V, int halfElems,
             unsigned long long* __restrict__ plist, int* __restrict__ pcnt,
             float* __restrict__ psum) {
  const int row = blockIdx.y, half = blockIdx.x, tid = threadIdx.x;
  const int wave = tid >> 6, lane = tid & 63;
  const float* lrow = logits + (size_t)row * V;
  const int start = half * halfElems;
  const int end = min(start + halfElems, V);
  __shared__ unsigned long long seg[NWAVES1][WSEG];
  __shared__ int wcnt[NWAVES1];
  __shared__ int wbase[NWAVES1];
  __shared__ int s_total, s_ovf;
  __shared__ float s_sum;
  if (tid < NWAVES1) wcnt[tid] = 0;
  if (tid == 0) { s_sum = 0.0f; s_ovf = 0; }
  __syncthreads();

  float s0 = 0.0f, s1 = 0.0f, s2 = 0.0f, s3 = 0.0f;
  const int n = max(end - start, 0);
  const int n4 = n >> 2;
  const float4* p4 = (const float4*)(lrow + start);
  int i = tid;
  for (; i + 3 * BLK1 < n4; i += 4 * BLK1) {
    float4 a0 = p4[i], a1 = p4[i + BLK1], a2 = p4[i + 2 * BLK1], a3 = p4[i + 3 * BLK1];
    float va[16] = {a0.x, a0.y, a0.z, a0.w, a1.x, a1.y, a1.z, a1.w,
                    a2.x, a2.y, a2.z, a2.w, a3.x, a3.y, a3.z, a3.w};
    #pragma unroll
    for (int c2 = 0; c2 < 16; c2++) {
      float x = va[c2];
      float e = __expf(fminf(x, 70.0f) - 6.0f);
      if (c2 < 4) s0 += e; else if (c2 < 8) s1 += e; else if (c2 < 12) s2 += e; else s3 += e;
      if (x >= BOUND) {
        int p = atomicAdd(&wcnt[wave], 1);
        if (p < WSEG) seg[wave][p] = pack_vi(x, start + ((i + (c2 >> 2) * BLK1) << 2) + (c2 & 3));
      }
    }
  }
  for (; i < n4; i += BLK1) {
    float4 a = p4[i];
    float va[4] = {a.x, a.y, a.z, a.w};
    #pragma unroll
    for (int c2 = 0; c2 < 4; c2++) {
      float x = va[c2];
      s0 += __expf(fminf(x, 70.0f) - 6.0f);
      if (x >= BOUND) {
        int p = atomicAdd(&wcnt[wave], 1);
        if (p < WSEG) seg[wave][p] = pack_vi(x, start + (i << 2) + c2);
      }
    }
  }
  for (int j = (n4 << 2) + tid; j < n; j += BLK1) {
    float x = lrow[start + j];
    s0 += __expf(fminf(x, 70.0f) - 6.0f);
    if (x >= BOUND) {
      int p = atomicAdd(&wcnt[wave], 1);
      if (p < WSEG) seg[wave][p] = pack_vi(x, start + j);
    }
  }
  // wave-level sum reduction, one LDS atomic per wave
  float s = (s0 + s1) + (s2 + s3);
  for (int o = 32; o > 0; o >>= 1) s += __shfl_down(s, o, 64);
  if (lane == 0) atomicAdd(&s_sum, s);
  __syncthreads();

  if (tid == 0) {
    int b = 0, ov = 0;
    for (int w = 0; w < NWAVES1; w++) {
      wbase[w] = b;
      int cw = wcnt[w];
      if (cw > WSEG) { ov = 1; cw = WSEG; }
      b += cw;
    }
    s_total = b; s_ovf = ov;
    const size_t rc = (size_t)row * 2 + half;
    psum[rc] = s_sum;
    pcnt[rc] = (ov || b > LCAP2) ? (LCAP2 + 1) : b;
  }
  __syncthreads();
  // coalesced per-wave copy-out
  {
    int cw = min(wcnt[wave], WSEG);
    int base = wbase[wave];
    unsigned long long* prow = plist + ((size_t)row * 2 + half) * LCAP2;
    for (int j = lane; j < cw; j += 64) {
      int pos = base + j;
      if (pos < LCAP2) prow[pos] = seg[wave][j];
    }
  }
}

// ---- k2: hist from pre-lists -> bstar -> counting sort -> chain -> sample ----
__global__ __launch_bounds__(BLK2)
void k2_fused(const float* __restrict__ logits,
              const float* __restrict__ temperature,
              const float* __restrict__ min_p,
              const int* __restrict__ top_k,
              const float* __restrict__ top_p,
              const float* __restrict__ q,
              const int* __restrict__ nl_ptr,
              int V, int B,
              const unsigned long long* __restrict__ plist,
              const int* __restrict__ pcnt,
              const float* __restrict__ psum,
              float* __restrict__ out) {
  const int row = blockIdx.x, tid = threadIdx.x;
  __shared__ int h[NB + 1];
  __shared__ int cur[NB];
  __shared__ unsigned long long lst[2 * LCAP2];
  __shared__ unsigned long long bkt[C_CAP];
  __shared__ float sv[C_CAP];
  __shared__ int   si[C_CAP];
  __shared__ float ss[C_CAP];
  __shared__ float st[BLK2];
  __shared__ float rf[BLK2], rf2[BLK2];
  __shared__ int   ri[BLK2];
  __shared__ int   s_fail, s_b;
  __shared__ float s_lse;

  for (int i = tid; i < NB; i += BLK2) { h[i] = 0; cur[i] = 0; }
  if (tid == 0) { s_b = 0; h[NB] = 0; }
  __syncthreads();

  const int p0 = pcnt[(size_t)row * 2], p1 = pcnt[(size_t)row * 2 + 1];
  const int c0 = min(p0, LCAP2), c1 = min(p1, LCAP2);
  const int tot = c0 + c1;
  int nl = nl_ptr[0];
  int ke = top_k[row]; ke = min(max(ke, 1), V);
  const int Kp = max(ke, nl);
  const bool fast = (p0 <= LCAP2) && (p1 <= LCAP2) && (tot >= Kp);

  if (tid == 0) s_lse = 6.0f + logf(psum[(size_t)row * 2] + psum[(size_t)row * 2 + 1]);

  const float* lrow = logits + (size_t)row * V;
  const int n4 = V >> 2;
  const float4* p4 = (const float4*)lrow;

  if (fast) {
    const unsigned long long* pr0 = plist + (size_t)row * 2 * LCAP2;
    const unsigned long long* pr1 = pr0 + LCAP2;
    for (int j = tid; j < c0; j += BLK2) lst[j] = pr0[j];
    for (int j = tid; j < c1; j += BLK2) lst[c0 + j] = pr1[j];
    __syncthreads();
    for (int j = tid; j < tot; j += BLK2) {
      float x = __uint_as_float((unsigned int)(lst[j] >> 32));
      atomicAdd(&h[bin_of(x)], 1);
    }
  } else {
    for (int ii = tid; ii < n4; ii += BLK2) {
      float4 a4 = p4[ii];
      atomicAdd(&h[bin_of(a4.x)], 1); atomicAdd(&h[bin_of(a4.y)], 1);
      atomicAdd(&h[bin_of(a4.z)], 1); atomicAdd(&h[bin_of(a4.w)], 1);
    }
    for (int j = (n4 << 2) + tid; j < V; j += BLK2)
      atomicAdd(&h[bin_of(lrow[j])], 1);
  }
  __syncthreads();

  // suffix-inclusive scan (2 elems/thread): h[i] = count in bins >= i
  for (int off = 1; off < NB; off <<= 1) {
    int i0 = tid, i1 = tid + BLK2;
    int t0 = (i0 + off < NB) ? h[i0 + off] : 0;
    int t1 = (i1 + off < NB) ? h[i1 + off] : 0;
    __syncthreads();
    h[i0] += t0; h[i1] += t1;
    __syncthreads();
  }
  if (h[tid] >= Kp) atomicMax(&s_b, tid);
  if (h[tid + BLK2] >= Kp) atomicMax(&s_b, tid + BLK2);
  __syncthreads();
  const int bstar = s_b;
  int c = min(h[bstar], C_CAP); if (c < 1) c = 1;

  // ingest into bin-grouped positions (base = h[b+1], per-bin cursor)
  if (fast) {
    for (int j = tid; j < tot; j += BLK2) {
      unsigned long long kk = lst[j];
      float x = __uint_as_float((unsigned int)(kk >> 32));
      int idx = (int)(unsigned int)kk;
      int b = bin_of(x);
      if (b >= bstar) {
        int a = atomicAdd(&cur[b], 1);
        int pos = h[b + 1] + a;
        if (pos < C_CAP) bkt[pos] = okey(x, idx);
      }
    }
  } else {
    for (int ii = tid; ii < n4; ii += BLK2) {
      float4 a4 = p4[ii];
      float va[4] = {a4.x, a4.y, a4.z, a4.w};
      #pragma unroll
      for (int c2 = 0; c2 < 4; c2++) {
        int b = bin_of(va[c2]);
        if (b >= bstar) {
          int a = atomicAdd(&cur[b], 1);
          int pos = h[b + 1] + a;
          if (pos < C_CAP) bkt[pos] = okey(va[c2], (ii << 2) + c2);
        }
      }
    }
    for (int j = (n4 << 2) + tid; j < V; j += BLK2) {
      float x = lrow[j];
      int b = bin_of(x);
      if (b >= bstar) {
        int a = atomicAdd(&cur[b], 1);
        int pos = h[b + 1] + a;
        if (pos < C_CAP) bkt[pos] = okey(x, j);
      }
    }
  }
  __syncthreads();

  // exact rank within bin -> sorted sv/si
  for (int pos = tid; pos < c; pos += BLK2) {
    unsigned long long k0 = bkt[pos];
    float v = okey_val(k0);
    int b = bin_of(v);
    int gs = h[b + 1];
    int ge = min(h[b], c);
    int rk = 0;
    for (int j = gs; j < ge; j++) if (bkt[j] > k0) rk++;
    int fin = gs + rk;
    sv[fin] = v; si[fin] = okey_idx(k0);
  }
  __syncthreads();

  // ---- filter chain ----
  float temp = temperature[row];
  bool ug = (temp < 1e-5f);
  float rt = 1.0f / (ug ? 1.0f : temp);
  float mp = min_p[row], tp = top_p[row];
  ke = min(ke, c);
  float v0 = sv[0];
  float lt0 = v0 * rt;

  float ltk = sv[ke - 1] * rt;
  float kth = (expf(ltk - lt0) >= mp) ? ltk : -INFINITY;

  if (tid == 0) s_fail = c;
  __syncthreads();
  for (int ii = tid; ii < c; ii += BLK2) {
    float ltj = sv[ii] * rt;
    if (!((expf(ltj - lt0) >= mp) && (ltj >= kth))) { atomicMin(&s_fail, ii); break; }
  }
  __syncthreads();
  int n1 = s_fail; if (n1 < 1) n1 = 1;
  __syncthreads();

  // segmented inclusive prefix scan of p_j over [0, c)
  int L = (c + BLK2 - 1) / BLK2;
  int base = tid * L;
  int lim = min(base + L, c);
  float run = 0.0f;
  for (int j = base; j < lim; j++) {
    float pj = (j < n1) ? expf(sv[j] * rt - lt0) : 0.0f;
    run += pj; ss[j] = run;
  }
  st[tid] = run;
  __syncthreads();
  for (int off = 1; off < BLK2; off <<= 1) {
    float t0 = (tid >= off) ? st[tid - off] : 0.0f;
    __syncthreads();
    st[tid] += t0;
    __syncthreads();
  }
  float offv = (tid > 0) ? st[tid - 1] : 0.0f;
  for (int j = base; j < lim; j++) ss[j] += offv;
  __syncthreads();
  float Z1 = ss[n1 - 1];

  if (tid == 0) s_fail = n1;
  __syncthreads();
  for (int ii = tid; ii < n1; ii += BLK2) {
    if (ii > 0 && !((1.0f - ss[ii - 1] / Z1) > (1.0f - tp))) { atomicMin(&s_fail, ii); break; }
  }
  __syncthreads();
  int n2 = s_fail; if (n2 < 1) n2 = 1;
  __syncthreads();
  float Z2 = ss[n2 - 1];

  const float* qrow = q + (size_t)row * V;
  float bsc = -INFINITY; int bidx = 0x7fffffff; float bval = 0.0f;
  for (int ii = tid; ii < n2; ii += BLK2) {
    float pj = expf(sv[ii] * rt - lt0);
    float qv = qrow[si[ii]];
    qv = fminf(fmaxf(qv, 1e-10f), 1.0f);
    float sc = (pj / Z2) / (-logf(qv));
    if (sc > bsc || (sc == bsc && si[ii] < bidx)) { bsc = sc; bidx = si[ii]; bval = sv[ii]; }
  }
  rf[tid] = bsc; ri[tid] = bidx; rf2[tid] = bval;
  __syncthreads();
  for (int s = BLK2 / 2; s > 0; s >>= 1) {
    if (tid < s) {
      if (rf[tid + s] > rf[tid] ||
          (rf[tid + s] == rf[tid] && ri[tid + s] < ri[tid])) {
        rf[tid] = rf[tid + s]; ri[tid] = ri[tid + s]; rf2[tid] = rf2[tid + s];
      }
    }
    __syncthreads();
  }
  int sampled = ug ? si[0] : ri[0];
  float val_s = ug ? sv[0] : rf2[0];
  float lse = s_lse;
  float tok_lp = val_s - lse;
  __syncthreads();

  if (tid == 0) s_fail = c;
  __syncthreads();
  for (int ii = tid; ii < c; ii += BLK2)
    if (!((sv[ii] - lse) >= tok_lp)) { atomicMin(&s_fail, ii); break; }
  __syncthreads();
  int rank = s_fail;

  int W = nl + 1;
  if (tid == 0) {
    out[row] = (float)sampled;
    out[B + row * W] = (float)sampled;
    out[B + B * W + row * W] = tok_lp;
    out[B + 2 * B * W + row] = (float)rank;
  }
  for (int t = tid; t < nl; t += BLK2) {
    out[B + row * W + 1 + t] = (float)si[t];
    out[B + B * W + row * W + 1 + t] = sv[t] - lse;
  }
}

extern "C" void kernel_launch(void* const* d_in, const int* in_sizes, int n_in,
                              void* d_out, int out_size, void* d_ws, size_t ws_size,
                              hipStream_t stream) {
  const float* logits      = (const float*)d_in[0];
  const float* temperature = (const float*)d_in[1];
  const float* min_p       = (const float*)d_in[2];
  const int*   top_k       = (const int*)d_in[3];
  const float* top_p       = (const float*)d_in[4];
  const float* q           = (const float*)d_in[5];
  const int*   nl_ptr      = (const int*)d_in[6];

  int B = in_sizes[1];
  int V = in_sizes[0] / B;
  float* out = (float*)d_out;
  int halfElems = (((V + 1) / 2) + 3) & ~3;

  unsigned char* w = (unsigned char*)d_ws;
  unsigned long long* plist = (unsigned long long*)w; w += (size_t)B * 2 * LCAP2 * sizeof(unsigned long long);
  int* pcnt = (int*)w;                                w += (size_t)B * 2 * sizeof(int);
  float* psum = (float*)w;                            w += (size_t)B * 2 * sizeof(float);

  hipLaunchKernelGGL(k1_scan, dim3(2, B), dim3(BLK1), 0, stream,
                     logits, V, halfElems, plist, pcnt, psum);
  hipLaunchKernelGGL(k2_fused, dim3(B), dim3(BLK2), 0, stream,
                     logits, temperature, min_p, top_k, top_p, q, nl_ptr,
                     V, B, plist, pcnt, psum, out);
}

// Round 9
// 157.207 us; speedup vs baseline: 1.1097x; 1.0598x over previous
//
#include <hip/hip_runtime.h>
#include <math.h>

#define NB 1024
#define C_CAP 2048
#define BLK1 512
#define BLK2 512
#define NW2 (BLK2 / 64)
#define NWAVES1 (BLK1 / 64)
#define WSEG 512             // per-wave segment cap (E[matches/wave]~181)
#define LCAP2 2048           // per half-row pre-list cap (expected ~1450)
#define FLOORB 682           // bin_of(1.9922); N(0,1): E[suffix] ~ 2900 >= Kp_max=1023
#define BIN_SCALE ((float)NB / 12.0f)
#define BOUND 1.9921875f     // -6 + FLOORB*12/NB

__device__ __forceinline__ int bin_of(float x) {
  int b = (int)floorf((x + 6.0f) * BIN_SCALE);
  return min(max(b, 0), NB - 1);
}
__device__ __forceinline__ unsigned long long pack_vi(float v, int idx) {
  return ((unsigned long long)__float_as_uint(v) << 32) | (unsigned int)idx;
}
// order key: value desc, idx asc
__device__ __forceinline__ unsigned long long okey(float v, int idx) {
  unsigned int u = __float_as_uint(v);
  u = (u & 0x80000000u) ? ~u : (u | 0x80000000u);
  return ((unsigned long long)u << 32) | (unsigned long long)(0x7fffffffu - (unsigned int)idx);
}
__device__ __forceinline__ float okey_val(unsigned long long k) {
  unsigned int hi = (unsigned int)(k >> 32);
  unsigned int u = (hi & 0x80000000u) ? (hi & 0x7fffffffu) : ~hi;
  return __uint_as_float(u);
}
__device__ __forceinline__ int okey_idx(unsigned long long k) {
  return (int)(0x7fffffffu - (unsigned int)k);
}

// ---- k1: stream half-row; sumexp + per-wave-segment pre-collect (unchanged) ----
__global__ __launch_bounds__(BLK1)
void k1_scan(const float* __restrict__ logits, int V, int halfElems,
             unsigned long long* __restrict__ plist, int* __restrict__ pcnt,
             float* __restrict__ psum) {
  const int row = blockIdx.y, half = blockIdx.x, tid = threadIdx.x;
  const int wave = tid >> 6, lane = tid & 63;
  const float* lrow = logits + (size_t)row * V;
  const int start = half * halfElems;
  const int end = min(start + halfElems, V);
  __shared__ unsigned long long seg[NWAVES1][WSEG];
  __shared__ int wcnt[NWAVES1];
  __shared__ int wbase[NWAVES1];
  __shared__ float s_sum;
  if (tid < NWAVES1) wcnt[tid] = 0;
  if (tid == 0) s_sum = 0.0f;
  __syncthreads();

  float s0 = 0.0f, s1 = 0.0f, s2 = 0.0f, s3 = 0.0f;
  const int n = max(end - start, 0);
  const int n4 = n >> 2;
  const float4* p4 = (const float4*)(lrow + start);
  int i = tid;
  for (; i + 3 * BLK1 < n4; i += 4 * BLK1) {
    float4 a0 = p4[i], a1 = p4[i + BLK1], a2 = p4[i + 2 * BLK1], a3 = p4[i + 3 * BLK1];
    float va[16] = {a0.x, a0.y, a0.z, a0.w, a1.x, a1.y, a1.z, a1.w,
                    a2.x, a2.y, a2.z, a2.w, a3.x, a3.y, a3.z, a3.w};
    #pragma unroll
    for (int c2 = 0; c2 < 16; c2++) {
      float x = va[c2];
      float e = __expf(fminf(x, 70.0f) - 6.0f);
      if (c2 < 4) s0 += e; else if (c2 < 8) s1 += e; else if (c2 < 12) s2 += e; else s3 += e;
      if (x >= BOUND) {
        int p = atomicAdd(&wcnt[wave], 1);
        if (p < WSEG) seg[wave][p] = pack_vi(x, start + ((i + (c2 >> 2) * BLK1) << 2) + (c2 & 3));
      }
    }
  }
  for (; i < n4; i += BLK1) {
    float4 a = p4[i];
    float va[4] = {a.x, a.y, a.z, a.w};
    #pragma unroll
    for (int c2 = 0; c2 < 4; c2++) {
      float x = va[c2];
      s0 += __expf(fminf(x, 70.0f) - 6.0f);
      if (x >= BOUND) {
        int p = atomicAdd(&wcnt[wave], 1);
        if (p < WSEG) seg[wave][p] = pack_vi(x, start + (i << 2) + c2);
      }
    }
  }
  for (int j = (n4 << 2) + tid; j < n; j += BLK1) {
    float x = lrow[start + j];
    s0 += __expf(fminf(x, 70.0f) - 6.0f);
    if (x >= BOUND) {
      int p = atomicAdd(&wcnt[wave], 1);
      if (p < WSEG) seg[wave][p] = pack_vi(x, start + j);
    }
  }
  float s = (s0 + s1) + (s2 + s3);
  for (int o = 32; o > 0; o >>= 1) s += __shfl_down(s, o, 64);
  if (lane == 0) atomicAdd(&s_sum, s);
  __syncthreads();

  if (tid == 0) {
    int b = 0, ov = 0;
    for (int w = 0; w < NWAVES1; w++) {
      wbase[w] = b;
      int cw = wcnt[w];
      if (cw > WSEG) { ov = 1; cw = WSEG; }
      b += cw;
    }
    const size_t rc = (size_t)row * 2 + half;
    psum[rc] = s_sum;
    pcnt[rc] = (ov || b > LCAP2) ? (LCAP2 + 1) : b;
  }
  __syncthreads();
  {
    int cw = min(wcnt[wave], WSEG);
    int base = wbase[wave];
    unsigned long long* prow = plist + ((size_t)row * 2 + half) * LCAP2;
    for (int j = lane; j < cw; j += 64) {
      int pos = base + j;
      if (pos < LCAP2) prow[pos] = seg[wave][j];
    }
  }
}

// ---- k2: wave-parallel primitives, minimal barriers ----
__global__ __launch_bounds__(BLK2)
void k2_fused(const float* __restrict__ logits,
              const float* __restrict__ temperature,
              const float* __restrict__ min_p,
              const int* __restrict__ top_k,
              const float* __restrict__ top_p,
              const float* __restrict__ q,
              const int* __restrict__ nl_ptr,
              int V, int B,
              const unsigned long long* __restrict__ plist,
              const int* __restrict__ pcnt,
              const float* __restrict__ psum,
              float* __restrict__ out) {
  const int row = blockIdx.x, tid = threadIdx.x;
  const int wave = tid >> 6, lane = tid & 63;
  __shared__ int h[NB + 1];
  __shared__ int cur[NB];
  __shared__ unsigned long long lst[2 * LCAP2];
  __shared__ unsigned long long bkt[C_CAP];
  __shared__ float sv[C_CAP];
  __shared__ int   si[C_CAP];
  __shared__ float ss[C_CAP];
  __shared__ float wtot[NW2];
  __shared__ float wb_sc[NW2], wb_vl[NW2];
  __shared__ int   wb_id[NW2];
  __shared__ int   s_n1, s_n2, s_rank, s_b;
  __shared__ float s_lse;

  for (int i = tid; i < NB; i += BLK2) { h[i] = 0; cur[i] = 0; }
  if (tid == 0) {
    h[NB] = 0; s_b = 0;
    s_n1 = 0x7fffffff; s_n2 = 0x7fffffff; s_rank = 0x7fffffff;
    s_lse = 6.0f + logf(psum[(size_t)row * 2] + psum[(size_t)row * 2 + 1]);
  }
  __syncthreads();

  const int p0 = pcnt[(size_t)row * 2], p1 = pcnt[(size_t)row * 2 + 1];
  const int c0 = min(p0, LCAP2), c1 = min(p1, LCAP2);
  const int tot = c0 + c1;
  int nl = nl_ptr[0];
  int ke = top_k[row]; ke = min(max(ke, 1), V);
  const int Kp = max(ke, nl);
  const bool fast = (p0 <= LCAP2) && (p1 <= LCAP2) && (tot >= Kp);

  const float* lrow = logits + (size_t)row * V;
  const int n4 = V >> 2;
  const float4* p4 = (const float4*)lrow;

  if (fast) {
    const unsigned long long* pr0 = plist + (size_t)row * 2 * LCAP2;
    const unsigned long long* pr1 = pr0 + LCAP2;
    for (int j = tid; j < c0; j += BLK2) lst[j] = pr0[j];
    for (int j = tid; j < c1; j += BLK2) lst[c0 + j] = pr1[j];
    __syncthreads();
    for (int j = tid; j < tot; j += BLK2) {
      float x = __uint_as_float((unsigned int)(lst[j] >> 32));
      atomicAdd(&h[bin_of(x)], 1);
    }
  } else {
    for (int ii = tid; ii < n4; ii += BLK2) {
      float4 a4 = p4[ii];
      atomicAdd(&h[bin_of(a4.x)], 1); atomicAdd(&h[bin_of(a4.y)], 1);
      atomicAdd(&h[bin_of(a4.z)], 1); atomicAdd(&h[bin_of(a4.w)], 1);
    }
    for (int j = (n4 << 2) + tid; j < V; j += BLK2)
      atomicAdd(&h[bin_of(lrow[j])], 1);
  }
  __syncthreads();

  // suffix scan + bstar: wave 0 alone (16 bins/lane, Kogge-Stone across lanes)
  if (wave == 0) {
    int hl[16];
    const int b16 = lane << 4;
    int lsum = 0;
    #pragma unroll
    for (int k = 0; k < 16; k++) { hl[k] = h[b16 + k]; lsum += hl[k]; }
    int s = lsum;
    #pragma unroll
    for (int o = 1; o < 64; o <<= 1) {
      int t = __shfl_down(s, o, 64);
      if (lane + o < 64) s += t;
    }
    int run = s - lsum;   // exclusive suffix (lanes > lane)
    int bst = 0;
    #pragma unroll
    for (int k = 15; k >= 0; k--) {
      run += hl[k];
      h[b16 + k] = run;
      if (run >= Kp) bst = max(bst, b16 + k);
    }
    #pragma unroll
    for (int o = 1; o < 64; o <<= 1) {
      int t = __shfl_down(bst, o, 64);
      if (lane + o < 64) bst = max(bst, t);
    }
    if (lane == 0) s_b = bst;
  }
  __syncthreads();
  const int bstar = s_b;
  int c = min(h[bstar], C_CAP); if (c < 1) c = 1;

  // ingest into bin-grouped positions (base = h[b+1], per-bin cursor)
  if (fast) {
    for (int j = tid; j < tot; j += BLK2) {
      unsigned long long kk = lst[j];
      float x = __uint_as_float((unsigned int)(kk >> 32));
      int idx = (int)(unsigned int)kk;
      int b = bin_of(x);
      if (b >= bstar) {
        int a = atomicAdd(&cur[b], 1);
        int pos = h[b + 1] + a;
        if (pos < C_CAP) bkt[pos] = okey(x, idx);
      }
    }
  } else {
    for (int ii = tid; ii < n4; ii += BLK2) {
      float4 a4 = p4[ii];
      float va[4] = {a4.x, a4.y, a4.z, a4.w};
      #pragma unroll
      for (int c2 = 0; c2 < 4; c2++) {
        int b = bin_of(va[c2]);
        if (b >= bstar) {
          int a = atomicAdd(&cur[b], 1);
          int pos = h[b + 1] + a;
          if (pos < C_CAP) bkt[pos] = okey(va[c2], (ii << 2) + c2);
        }
      }
    }
    for (int j = (n4 << 2) + tid; j < V; j += BLK2) {
      float x = lrow[j];
      int b = bin_of(x);
      if (b >= bstar) {
        int a = atomicAdd(&cur[b], 1);
        int pos = h[b + 1] + a;
        if (pos < C_CAP) bkt[pos] = okey(x, j);
      }
    }
  }
  __syncthreads();

  // exact rank within bin -> sorted sv/si
  for (int pos = tid; pos < c; pos += BLK2) {
    unsigned long long k0 = bkt[pos];
    float v = okey_val(k0);
    int b = bin_of(v);
    int gs = h[b + 1];
    int ge = min(h[b], c);
    int rk = 0;
    for (int j = gs; j < ge; j++) if (bkt[j] > k0) rk++;
    int fin = gs + rk;
    sv[fin] = v; si[fin] = okey_idx(k0);
  }
  __syncthreads();

  // ---- filter chain ----
  float temp = temperature[row];
  bool ug = (temp < 1e-5f);
  float rt = 1.0f / (ug ? 1.0f : temp);
  float mp = min_p[row], tp = top_p[row];
  ke = min(ke, c);
  float v0 = sv[0];
  float lt0 = v0 * rt;

  float ltk = sv[ke - 1] * rt;
  float kth = (expf(ltk - lt0) >= mp) ? ltk : -INFINITY;

  // n1: first fail of (min-p AND top-k). local min -> wave min -> 1 atomic/wave
  {
    int lm = 0x7fffffff;
    for (int ii = tid; ii < c; ii += BLK2) {
      float ltj = sv[ii] * rt;
      if (!((expf(ltj - lt0) >= mp) && (ltj >= kth))) { lm = ii; break; }
    }
    #pragma unroll
    for (int o = 1; o < 64; o <<= 1) {
      int t = __shfl_down(lm, o, 64);
      if (lane + o < 64) lm = min(lm, t);
    }
    if (lane == 0 && lm != 0x7fffffff) atomicMin(&s_n1, lm);
  }
  __syncthreads();
  int n1 = min(s_n1, c); if (n1 < 1) n1 = 1;

  // p-scan over [0, c): serial chunk -> wave shuffle scan -> cross-wave offsets
  int L = (c + BLK2 - 1) / BLK2;
  int base = tid * L;
  int lim = min(base + L, c);
  float run = 0.0f;
  for (int j = base; j < lim; j++) {
    float pj = (j < n1) ? expf(sv[j] * rt - lt0) : 0.0f;
    run += pj; ss[j] = run;
  }
  float v = run;
  #pragma unroll
  for (int o = 1; o < 64; o <<= 1) {
    float t = __shfl_up(v, o, 64);
    if (lane >= o) v += t;
  }
  if (lane == 63) wtot[wave] = v;
  __syncthreads();
  float woff = 0.0f;
  for (int w2 = 0; w2 < wave; w2++) woff += wtot[w2];
  float myoff = woff + (v - run);
  for (int j = base; j < lim; j++) ss[j] += myoff;
  __syncthreads();
  float Z1 = ss[n1 - 1];

  // top-p cut
  {
    int lm = 0x7fffffff;
    for (int ii = tid; ii < n1; ii += BLK2) {
      if (ii > 0 && !((1.0f - ss[ii - 1] / Z1) > (1.0f - tp))) { lm = ii; break; }
    }
    #pragma unroll
    for (int o = 1; o < 64; o <<= 1) {
      int t = __shfl_down(lm, o, 64);
      if (lane + o < 64) lm = min(lm, t);
    }
    if (lane == 0 && lm != 0x7fffffff) atomicMin(&s_n2, lm);
  }
  __syncthreads();
  int n2 = min(s_n2, n1); if (n2 < 1) n2 = 1;
  float Z2 = ss[n2 - 1];

  // exponential race: local best -> wave reduce -> 8 entries -> all scan
  const float* qrow = q + (size_t)row * V;
  float bsc = -INFINITY; int bidx = 0x7fffffff; float bval = 0.0f;
  for (int ii = tid; ii < n2; ii += BLK2) {
    float pj = expf(sv[ii] * rt - lt0);
    float qv = qrow[si[ii]];
    qv = fminf(fmaxf(qv, 1e-10f), 1.0f);
    float sc = (pj / Z2) / (-logf(qv));
    if (sc > bsc || (sc == bsc && si[ii] < bidx)) { bsc = sc; bidx = si[ii]; bval = sv[ii]; }
  }
  #pragma unroll
  for (int o = 1; o < 64; o <<= 1) {
    float sc2 = __shfl_down(bsc, o, 64);
    int   id2 = __shfl_down(bidx, o, 64);
    float vl2 = __shfl_down(bval, o, 64);
    if (lane + o < 64) {
      if (sc2 > bsc || (sc2 == bsc && id2 < bidx)) { bsc = sc2; bidx = id2; bval = vl2; }
    }
  }
  if (lane == 0) { wb_sc[wave] = bsc; wb_id[wave] = bidx; wb_vl[wave] = bval; }
  __syncthreads();
  float fsc = wb_sc[0]; int fid = wb_id[0]; float fvl = wb_vl[0];
  #pragma unroll
  for (int w2 = 1; w2 < NW2; w2++) {
    float sc2 = wb_sc[w2]; int id2 = wb_id[w2]; float vl2 = wb_vl[w2];
    if (sc2 > fsc || (sc2 == fsc && id2 < fid)) { fsc = sc2; fid = id2; fvl = vl2; }
  }
  int sampled = ug ? si[0] : fid;
  float val_s = ug ? sv[0] : fvl;
  float lse = s_lse;
  float tok_lp = val_s - lse;

  // rank: first fail of (sv - lse) >= tok_lp
  {
    int lm = 0x7fffffff;
    for (int ii = tid; ii < c; ii += BLK2)
      if (!((sv[ii] - lse) >= tok_lp)) { lm = ii; break; }
    #pragma unroll
    for (int o = 1; o < 64; o <<= 1) {
      int t = __shfl_down(lm, o, 64);
      if (lane + o < 64) lm = min(lm, t);
    }
    if (lane == 0 && lm != 0x7fffffff) atomicMin(&s_rank, lm);
  }
  __syncthreads();
  int rank = min(s_rank, c);

  int W = nl + 1;
  if (tid == 0) {
    out[row] = (float)sampled;
    out[B + row * W] = (float)sampled;
    out[B + B * W + row * W] = tok_lp;
    out[B + 2 * B * W + row] = (float)rank;
  }
  for (int t = tid; t < nl; t += BLK2) {
    out[B + row * W + 1 + t] = (float)si[t];
    out[B + B * W + row * W + 1 + t] = sv[t] - lse;
  }
}

extern "C" void kernel_launch(void* const* d_in, const int* in_sizes, int n_in,
                              void* d_out, int out_size, void* d_ws, size_t ws_size,
                              hipStream_t stream) {
  const float* logits      = (const float*)d_in[0];
  const float* temperature = (const float*)d_in[1];
  const float* min_p       = (const float*)d_in[2];
  const int*   top_k       = (const int*)d_in[3];
  const float* top_p       = (const float*)d_in[4];
  const float* q           = (const float*)d_in[5];
  const int*   nl_ptr      = (const int*)d_in[6];

  int B = in_sizes[1];
  int V = in_sizes[0] / B;
  float* out = (float*)d_out;
  int halfElems = (((V + 1) / 2) + 3) & ~3;

  unsigned char* w = (unsigned char*)d_ws;
  unsigned long long* plist = (unsigned long long*)w; w += (size_t)B * 2 * LCAP2 * sizeof(unsigned long long);
  int* pcnt = (int*)w;                                w += (size_t)B * 2 * sizeof(int);
  float* psum = (float*)w;                            w += (size_t)B * 2 * sizeof(float);

  hipLaunchKernelGGL(k1_scan, dim3(2, B), dim3(BLK1), 0, stream,
                     logits, V, halfElems, plist, pcnt, psum);
  hipLaunchKernelGGL(k2_fused, dim3(B), dim3(BLK2), 0, stream,
                     logits, temperature, min_p, top_k, top_p, q, nl_ptr,
                     V, B, plist, pcnt, psum, out);
}